// Round 3
// baseline (541.263 us; speedup 1.0000x reference)
//
#include <hip/hip_runtime.h>
#include <hip/hip_bf16.h>

#define NCELLS 256
#define DIM    512
#define NTOK   131072

typedef __attribute__((ext_vector_type(8))) short  bf16x8;
typedef __attribute__((ext_vector_type(4))) float  f32x4;
typedef __attribute__((ext_vector_type(4))) short  s16x4;

static __device__ __forceinline__ unsigned short f2bf(float f) {
    union { float f; unsigned u; } v; v.f = f;
    unsigned r = v.u + 0x7fffu + ((v.u >> 16) & 1u);
    return (unsigned short)(r >> 16);
}
static __device__ __forceinline__ float bf2f(unsigned short h) {
    union { unsigned u; float f; } v; v.u = ((unsigned)h) << 16;
    return v.f;
}
static __device__ __forceinline__ bf16x8 cvt8(f32x4 a, f32x4 b) {
    bf16x8 r;
    r[0] = (short)f2bf(a[0]); r[1] = (short)f2bf(a[1]);
    r[2] = (short)f2bf(a[2]); r[3] = (short)f2bf(a[3]);
    r[4] = (short)f2bf(b[0]); r[5] = (short)f2bf(b[1]);
    r[6] = (short)f2bf(b[2]); r[7] = (short)f2bf(b[3]);
    return r;
}

// stage one 8 KB chunk (4096 ushorts) global->LDS, 512 threads, 1 x 16B each.
// LDS dest linear in lane order (rule #21 safe); swizzle lives in the GLOBAL layout.
static __device__ __forceinline__ void stage8k(const unsigned short* __restrict__ gsrc,
                                               unsigned short* l, int tid) {
    __builtin_amdgcn_global_load_lds(
        (const __attribute__((address_space(1))) unsigned int*)(gsrc + tid * 8),
        (__attribute__((address_space(3))) unsigned int*)(l + tid * 8),
        16, 0, 0);
}

// ---------------- prep: pre-swizzled bf16 layouts + norms + gate + 1/T ----------------
// pcombL: 64 chunks of 8 KB = [16 cell-rows][256 dims]; chunk ct*4 + {0,1}=proto half0/1,
//         ct*4 + {2,3}=grid half0/1. Within a row, 16B-unit kb stored at kb^(row&7).
// protoTL: 32 chunks of 8 KB = [16 dim-rows][256 cells]; unit cb stored at cb^(dimrow&7).
__global__ void __launch_bounds__(256) prep_kernel(
        const float* __restrict__ proto, const float* __restrict__ grid,
        const float* __restrict__ temp_raw, const float* __restrict__ gate_logits,
        unsigned short* __restrict__ pcombL,
        unsigned short* __restrict__ protoTL,
        float* __restrict__ pp, float* __restrict__ gg,
        float* __restrict__ gate, float* __restrict__ invT)
{
    const int c = blockIdx.x;   // cell 0..255
    const int t = threadIdx.x;  // 0..255
    const int rl = c & 15, ct = c >> 4;
    float sp = 0.f, sg = 0.f;
    for (int i = t; i < DIM; i += 256) {
        float pv = proto[c * DIM + i];
        float gv = grid[c * DIM + i];
        const int h = i >> 8, kb2 = (i & 255) >> 3, e = i & 7;
        const int roff = rl * 256 + ((kb2 ^ (rl & 7)) << 3) + e;
        pcombL[(ct * 4 + h) * 4096 + roff]     = f2bf(pv);
        pcombL[(ct * 4 + 2 + h) * 4096 + roff] = f2bf(gv);
        const int d2 = i >> 4, rowd = i & 15;
        protoTL[d2 * 4096 + rowd * 256 + (((c >> 3) ^ (i & 7)) << 3) + (c & 7)] = f2bf(pv);
        sp += pv * pv; sg += gv * gv;
    }
    for (int m = 1; m < 64; m <<= 1) { sp += __shfl_xor(sp, m); sg += __shfl_xor(sg, m); }
    __shared__ float redp[4], redg[4];
    const int wv = t >> 6;
    if ((t & 63) == 0) { redp[wv] = sp; redg[wv] = sg; }
    __syncthreads();
    if (t == 0) {
        pp[c] = redp[0] + redp[1] + redp[2] + redp[3];
        gg[c] = redg[0] + redg[1] + redg[2] + redg[3];
        gate[c] = 1.f / (1.f + expf(-gate_logits[c]));
        if (c == 0) {
            float T = (1.f / (1.f + expf(-temp_raw[0]))) * (1.f - 0.001f) + 0.001f;
            invT[0] = 1.f / T;
        }
    }
}

// wait own vmcnt to N, then block barrier, then compiler memory fence.
#define WAIT_BAR(N) do { \
    asm volatile("s_waitcnt vmcnt(" #N ")" ::: "memory"); \
    __builtin_amdgcn_s_barrier(); \
    asm volatile("" ::: "memory"); \
} while (0)

// ---------------- main fused kernel ----------------
// 8 waves/block (512 thr), 16 tokens/wave, 128 tokens/block, 1024 blocks.
// LDS = 16 KB staging (2x8KB dbuf) + 64 KB W  = 80 KB -> 2 blocks/CU (16 waves/CU).
// Shift-softmax: z = 64 - d_total/T  (z<=64 always since d>=0) -> exp never overflows
// (sum <= 256*e^64 ~ 1.6e30) and cannot all-underflow -> NO max pass, NO z storage.
__global__ void __launch_bounds__(512, 4) som_main(
        const float* __restrict__ x,
        const unsigned short* __restrict__ pcombL,
        const unsigned short* __restrict__ protoTL,
        const float* __restrict__ pp, const float* __restrict__ gg,
        const float* __restrict__ gate, const float* __restrict__ invTp,
        float* __restrict__ out_blend, float* __restrict__ out_w)
{
    const int tid  = threadIdx.x;
    const int lane = tid & 63;
    const int wv   = tid >> 6;                    // 0..7
    const int tb   = blockIdx.x * 128 + wv * 16;  // wave's token base
    const int r    = lane & 15;
    const int g    = lane >> 4;
    const int k8   = g * 8;

    __shared__ __align__(16) unsigned short sbuf[2][4096];      // 16 KB staging
    __shared__ __align__(16) unsigned short lds_w[8][16][256];  // 64 KB gated-exp (bf16, swizzled)

    const float invT = invTp[0];

    // prologue: stage pcombL chunk 0 (lands during phase 1)
    stage8k(pcombL, sbuf[0], tid);

    // ---- Phase 1: x tile -> A fragments (bf16) + |x|^2 (fp32) ----
    bf16x8 a1[16];
    float xx_part = 0.f;
    const float* xrow = x + (size_t)(tb + r) * DIM;
    #pragma unroll
    for (int ks = 0; ks < 16; ++ks) {
        const f32x4* p0 = (const f32x4*)(xrow + ks * 32 + k8);
        f32x4 u0 = p0[0], u1 = p0[1];
        #pragma unroll
        for (int i = 0; i < 4; ++i) xx_part += u0[i] * u0[i] + u1[i] * u1[i];
        a1[ks] = cvt8(u0, u1);
    }
    xx_part += __shfl_xor(xx_part, 16);
    xx_part += __shfl_xor(xx_part, 32);
    float xt[4];
    #pragma unroll
    for (int j = 0; j < 4; ++j) xt[j] = __shfl(xx_part, g * 4 + j);

    // ---- Phase 2: 64 chunks; streaming shift-softmax, e' -> lds_w immediately ----
    // chunk body: wait(own stage done) -> barrier -> issue next stage -> 8 ds_read + 8 MFMA
    #define CHUNK(ACC, HB, CH) do { \
        WAIT_BAR(0); \
        stage8k(((CH) < 63 ? pcombL + ((CH) + 1) * 4096 : protoTL), sbuf[((CH) + 1) & 1], tid); \
        const unsigned short* bb = sbuf[(CH) & 1]; \
        _Pragma("unroll") \
        for (int ks = 0; ks < 8; ++ks) { \
            bf16x8 b = *(const bf16x8*)(bb + r * 256 + (((ks * 4 + g) ^ (r & 7)) << 3)); \
            ACC = __builtin_amdgcn_mfma_f32_16x16x32_bf16(a1[(HB) * 8 + ks], b, ACC, 0, 0, 0); \
        } \
    } while (0)

    float s1[4] = {0.f, 0.f, 0.f, 0.f};
    float s2[4] = {0.f, 0.f, 0.f, 0.f};
    #pragma unroll
    for (int ctl = 0; ctl < 16; ++ctl) {
        f32x4 accP = {0.f, 0.f, 0.f, 0.f};
        f32x4 accG = {0.f, 0.f, 0.f, 0.f};
        CHUNK(accP, 0, ctl * 4 + 0);
        CHUNK(accP, 1, ctl * 4 + 1);
        CHUNK(accG, 0, ctl * 4 + 2);
        CHUNK(accG, 1, ctl * 4 + 3);
        const int cell = ctl * 16 + r;
        const float ppc = pp[cell], ggc = gg[cell], gtc = gate[cell];
        #pragma unroll
        for (int j = 0; j < 4; ++j) {
            float dp = sqrtf(fmaxf(xt[j] + ppc - 2.f * accP[j], 0.f));
            float dg = sqrtf(fmaxf(xt[j] + ggc - 2.f * accG[j], 0.f));
            float zj = 64.f - (dp + dg) * invT;
            float ep = __expf(zj);
            float eg = ep * gtc;
            s1[j] += ep;
            s2[j] += eg;
            const int tok = g * 4 + j;
            lds_w[wv][tok][(((ctl * 2 + (r >> 3)) ^ (tok & 7)) << 3) + (r & 7)] = f2bf(eg);
        }
    }
    #undef CHUNK

    // ---- Phase 3: denominators (reduce within 16-lane group) ----
    float rden[4];
    #pragma unroll
    for (int j = 0; j < 4; ++j) {
        float a = s1[j], b = s2[j];
        a += __shfl_xor(a, 1); b += __shfl_xor(b, 1);
        a += __shfl_xor(a, 2); b += __shfl_xor(b, 2);
        a += __shfl_xor(a, 4); b += __shfl_xor(b, 4);
        a += __shfl_xor(a, 8); b += __shfl_xor(b, 8);
        rden[j] = 1.f / (b + 1e-8f * a);
    }

    // ---- Phase 4: weights out (full-line dwordx4 stores, read back own wave's lds_w) ----
    float* wout = out_w + (size_t)tb * NCELLS;
    #pragma unroll
    for (int t0 = 0; t0 < 16; ++t0) {
        float rdt = __shfl(rden[t0 & 3], (t0 >> 2) * 16);
        const int addr = (((lane >> 1) ^ (t0 & 7)) << 3) + (lane & 1) * 4;
        s16x4 q = *(const s16x4*)&lds_w[wv][t0][addr];
        f32x4 o;
        o[0] = bf2f((unsigned short)q[0]) * rdt;
        o[1] = bf2f((unsigned short)q[1]) * rdt;
        o[2] = bf2f((unsigned short)q[2]) * rdt;
        o[3] = bf2f((unsigned short)q[3]) * rdt;
        *(f32x4*)&wout[(size_t)t0 * NCELLS + lane * 4] = o;
    }

    // ---- Phase 5: blended = (e' @ proto) * rden, 32 chunks of 16 dim-rows ----
    bf16x8 aw[8];
    #pragma unroll
    for (int ks = 0; ks < 8; ++ks)
        aw[ks] = *(const bf16x8*)&lds_w[wv][r][((ks * 4 + g) ^ (r & 7)) << 3];

    float* bout = out_blend + (size_t)tb * DIM;
    for (int d2 = 0; d2 < 32; ++d2) {
        WAIT_BAR(4);   // allow ~4 newest stores in flight; forces the (older) stage done
        if (d2 < 31) stage8k(protoTL + (d2 + 1) * 4096, sbuf[(d2 + 1) & 1], tid);
        const unsigned short* bb = sbuf[d2 & 1];
        f32x4 acc = {0.f, 0.f, 0.f, 0.f};
        #pragma unroll
        for (int ks = 0; ks < 8; ++ks) {
            bf16x8 b = *(const bf16x8*)(bb + r * 256 + (((ks * 4 + g) ^ (r & 7)) << 3));
            acc = __builtin_amdgcn_mfma_f32_16x16x32_bf16(aw[ks], b, acc, 0, 0, 0);
        }
        #pragma unroll
        for (int j = 0; j < 4; ++j)
            bout[(size_t)(g * 4 + j) * DIM + d2 * 16 + r] = acc[j] * rden[j];
    }
}

// ---------------- launch ----------------
extern "C" void kernel_launch(void* const* d_in, const int* in_sizes, int n_in,
                              void* d_out, int out_size, void* d_ws, size_t ws_size,
                              hipStream_t stream) {
    const float* x           = (const float*)d_in[0];
    const float* proto       = (const float*)d_in[1];
    const float* grid        = (const float*)d_in[2];
    const float* temp_raw    = (const float*)d_in[3];
    const float* gate_logits = (const float*)d_in[4];

    float* out       = (float*)d_out;
    float* out_blend = out;                          // [N][512]
    float* out_w     = out + (size_t)NTOK * DIM;     // [N][256]

    char* ws = (char*)d_ws;
    unsigned short* pcombL  = (unsigned short*)(ws);            // 524288 B
    unsigned short* protoTL = (unsigned short*)(ws + 524288);   // 262144 B
    float* pp   = (float*)(ws + 786432);
    float* gg   = (float*)(ws + 787456);
    float* gate = (float*)(ws + 788480);
    float* invT = (float*)(ws + 789504);

    prep_kernel<<<dim3(NCELLS), dim3(256), 0, stream>>>(
        proto, grid, temp_raw, gate_logits, pcombL, protoTL, pp, gg, gate, invT);
    som_main<<<dim3(NTOK / 128), dim3(512), 0, stream>>>(
        x, pcombL, protoTL, pp, gg, gate, invT, out_blend, out_w);
}

// Round 4
// 355.535 us; speedup vs baseline: 1.5224x; 1.5224x over previous
//
#include <hip/hip_runtime.h>
#include <hip/hip_bf16.h>

#define NCELLS 256
#define DIM    512
#define NTOK   131072

typedef __attribute__((ext_vector_type(8))) short  bf16x8;
typedef __attribute__((ext_vector_type(4))) float  f32x4;
typedef __attribute__((ext_vector_type(4))) short  s16x4;

static __device__ __forceinline__ unsigned short f2bf(float f) {
    union { float f; unsigned u; } v; v.f = f;
    unsigned r = v.u + 0x7fffu + ((v.u >> 16) & 1u);
    return (unsigned short)(r >> 16);
}
static __device__ __forceinline__ float bf2f(unsigned short h) {
    union { unsigned u; float f; } v; v.u = ((unsigned)h) << 16;
    return v.f;
}
static __device__ __forceinline__ bf16x8 cvt8(f32x4 a, f32x4 b) {
    bf16x8 r;
    r[0] = (short)f2bf(a[0]); r[1] = (short)f2bf(a[1]);
    r[2] = (short)f2bf(a[2]); r[3] = (short)f2bf(a[3]);
    r[4] = (short)f2bf(b[0]); r[5] = (short)f2bf(b[1]);
    r[6] = (short)f2bf(b[2]); r[7] = (short)f2bf(b[3]);
    return r;
}

// stage one 8 KB chunk (4096 ushorts) global->LDS, 512 threads, 1 x 16B each.
// LDS dest linear in lane order (rule #21 safe); swizzle lives in the GLOBAL layout.
static __device__ __forceinline__ void stage8k(const unsigned short* __restrict__ gsrc,
                                               unsigned short* l, int tid) {
    __builtin_amdgcn_global_load_lds(
        (const __attribute__((address_space(1))) unsigned int*)(gsrc + tid * 8),
        (__attribute__((address_space(3))) unsigned int*)(l + tid * 8),
        16, 0, 0);
}

// ---------------- prep: pre-swizzled bf16 layouts + norms + gate + 1/T ----------------
// pcombL: 64 chunks of 8 KB = [16 cell-rows][256 dims]; chunk ct*4 + {0,1}=proto half0/1,
//         ct*4 + {2,3}=grid half0/1. Within a row, 16B-unit kb stored at kb^(row&7).
// protoTL: 32 chunks of 8 KB = [16 dim-rows][256 cells]; unit cb stored at cb^(dimrow&7).
__global__ void __launch_bounds__(256) prep_kernel(
        const float* __restrict__ proto, const float* __restrict__ grid,
        const float* __restrict__ temp_raw, const float* __restrict__ gate_logits,
        unsigned short* __restrict__ pcombL,
        unsigned short* __restrict__ protoTL,
        float* __restrict__ pp, float* __restrict__ gg,
        float* __restrict__ gate, float* __restrict__ invT)
{
    const int c = blockIdx.x;   // cell 0..255
    const int t = threadIdx.x;  // 0..255
    const int rl = c & 15, ct = c >> 4;
    float sp = 0.f, sg = 0.f;
    for (int i = t; i < DIM; i += 256) {
        float pv = proto[c * DIM + i];
        float gv = grid[c * DIM + i];
        const int h = i >> 8, kb2 = (i & 255) >> 3, e = i & 7;
        const int roff = rl * 256 + ((kb2 ^ (rl & 7)) << 3) + e;
        pcombL[(ct * 4 + h) * 4096 + roff]     = f2bf(pv);
        pcombL[(ct * 4 + 2 + h) * 4096 + roff] = f2bf(gv);
        const int d2 = i >> 4, rowd = i & 15;
        protoTL[d2 * 4096 + rowd * 256 + (((c >> 3) ^ (i & 7)) << 3) + (c & 7)] = f2bf(pv);
        sp += pv * pv; sg += gv * gv;
    }
    for (int m = 1; m < 64; m <<= 1) { sp += __shfl_xor(sp, m); sg += __shfl_xor(sg, m); }
    __shared__ float redp[4], redg[4];
    const int wv = t >> 6;
    if ((t & 63) == 0) { redp[wv] = sp; redg[wv] = sg; }
    __syncthreads();
    if (t == 0) {
        pp[c] = redp[0] + redp[1] + redp[2] + redp[3];
        gg[c] = redg[0] + redg[1] + redg[2] + redg[3];
        gate[c] = 1.f / (1.f + expf(-gate_logits[c]));
        if (c == 0) {
            float T = (1.f / (1.f + expf(-temp_raw[0]))) * (1.f - 0.001f) + 0.001f;
            invT[0] = 1.f / T;
        }
    }
}

// wait own vmcnt to N, then block barrier, then compiler memory fence.
#define WAIT_BAR(N) do { \
    asm volatile("s_waitcnt vmcnt(" #N ")" ::: "memory"); \
    __builtin_amdgcn_s_barrier(); \
    asm volatile("" ::: "memory"); \
} while (0)

// ---------------- main fused kernel ----------------
// 8 waves/block (512 thr), 16 tokens/wave, 128 tokens/block, 1024 blocks.
// LDS = 16 KB staging (2x8KB dbuf) + 64 KB W  = 80 KB -> 2 blocks/CU (16 waves/CU).
// __launch_bounds__(512, 2): 2 blocks/CU -> 16 waves/CU -> 128-VGPR cap.
// (512, 4) capped VGPR at 64 -> a1[16] spilled -> +1 GB scratch traffic (round 3).
// Shift-softmax: z = 64 - d_total/T  (z<=64 always since d>=0) -> exp never overflows
// (sum <= 256*e^64 ~ 1.6e30) and cannot all-underflow -> NO max pass, NO z storage.
__global__ void __launch_bounds__(512, 2) som_main(
        const float* __restrict__ x,
        const unsigned short* __restrict__ pcombL,
        const unsigned short* __restrict__ protoTL,
        const float* __restrict__ pp, const float* __restrict__ gg,
        const float* __restrict__ gate, const float* __restrict__ invTp,
        float* __restrict__ out_blend, float* __restrict__ out_w)
{
    const int tid  = threadIdx.x;
    const int lane = tid & 63;
    const int wv   = tid >> 6;                    // 0..7
    const int tb   = blockIdx.x * 128 + wv * 16;  // wave's token base
    const int r    = lane & 15;
    const int g    = lane >> 4;
    const int k8   = g * 8;

    __shared__ __align__(16) unsigned short sbuf[2][4096];      // 16 KB staging
    __shared__ __align__(16) unsigned short lds_w[8][16][256];  // 64 KB gated-exp (bf16, swizzled)

    const float invT = invTp[0];

    // prologue: stage pcombL chunk 0 (lands during phase 1)
    stage8k(pcombL, sbuf[0], tid);

    // ---- Phase 1: x tile -> A fragments (bf16) + |x|^2 (fp32) ----
    bf16x8 a1[16];
    float xx_part = 0.f;
    const float* xrow = x + (size_t)(tb + r) * DIM;
    #pragma unroll
    for (int ks = 0; ks < 16; ++ks) {
        const f32x4* p0 = (const f32x4*)(xrow + ks * 32 + k8);
        f32x4 u0 = p0[0], u1 = p0[1];
        #pragma unroll
        for (int i = 0; i < 4; ++i) xx_part += u0[i] * u0[i] + u1[i] * u1[i];
        a1[ks] = cvt8(u0, u1);
    }
    xx_part += __shfl_xor(xx_part, 16);
    xx_part += __shfl_xor(xx_part, 32);
    float xt[4];
    #pragma unroll
    for (int j = 0; j < 4; ++j) xt[j] = __shfl(xx_part, g * 4 + j);

    // ---- Phase 2: 64 chunks; streaming shift-softmax, e' -> lds_w immediately ----
    // chunk body: wait(own stage done) -> barrier -> issue next stage -> 8 ds_read + 8 MFMA
    #define CHUNK(ACC, HB, CH) do { \
        WAIT_BAR(0); \
        stage8k(((CH) < 63 ? pcombL + ((CH) + 1) * 4096 : protoTL), sbuf[((CH) + 1) & 1], tid); \
        const unsigned short* bb = sbuf[(CH) & 1]; \
        _Pragma("unroll") \
        for (int ks = 0; ks < 8; ++ks) { \
            bf16x8 b = *(const bf16x8*)(bb + r * 256 + (((ks * 4 + g) ^ (r & 7)) << 3)); \
            ACC = __builtin_amdgcn_mfma_f32_16x16x32_bf16(a1[(HB) * 8 + ks], b, ACC, 0, 0, 0); \
        } \
    } while (0)

    float s1[4] = {0.f, 0.f, 0.f, 0.f};
    float s2[4] = {0.f, 0.f, 0.f, 0.f};
    // NOT unrolled: keeps pp/gg/gate loads inside each iteration (no 48-reg hoist),
    // all register arrays (a1, s1, s2) still statically indexed inside.
    #pragma unroll 1
    for (int ctl = 0; ctl < 16; ++ctl) {
        f32x4 accP = {0.f, 0.f, 0.f, 0.f};
        f32x4 accG = {0.f, 0.f, 0.f, 0.f};
        CHUNK(accP, 0, ctl * 4 + 0);
        CHUNK(accP, 1, ctl * 4 + 1);
        CHUNK(accG, 0, ctl * 4 + 2);
        CHUNK(accG, 1, ctl * 4 + 3);
        const int cell = ctl * 16 + r;
        const float ppc = pp[cell], ggc = gg[cell], gtc = gate[cell];
        #pragma unroll
        for (int j = 0; j < 4; ++j) {
            float dp = sqrtf(fmaxf(xt[j] + ppc - 2.f * accP[j], 0.f));
            float dg = sqrtf(fmaxf(xt[j] + ggc - 2.f * accG[j], 0.f));
            float zj = 64.f - (dp + dg) * invT;
            float ep = __expf(zj);
            float eg = ep * gtc;
            s1[j] += ep;
            s2[j] += eg;
            const int tok = g * 4 + j;
            lds_w[wv][tok][(((ctl * 2 + (r >> 3)) ^ (tok & 7)) << 3) + (r & 7)] = f2bf(eg);
        }
    }
    #undef CHUNK

    // ---- Phase 3: denominators (reduce within 16-lane group) ----
    float rden[4];
    #pragma unroll
    for (int j = 0; j < 4; ++j) {
        float a = s1[j], b = s2[j];
        a += __shfl_xor(a, 1); b += __shfl_xor(b, 1);
        a += __shfl_xor(a, 2); b += __shfl_xor(b, 2);
        a += __shfl_xor(a, 4); b += __shfl_xor(b, 4);
        a += __shfl_xor(a, 8); b += __shfl_xor(b, 8);
        rden[j] = 1.f / (b + 1e-8f * a);
    }

    // ---- Phase 4: weights out (full-line dwordx4 stores, read back own wave's lds_w) ----
    float* wout = out_w + (size_t)tb * NCELLS;
    #pragma unroll
    for (int t0 = 0; t0 < 16; ++t0) {
        float rdt = __shfl(rden[t0 & 3], (t0 >> 2) * 16);
        const int addr = (((lane >> 1) ^ (t0 & 7)) << 3) + (lane & 1) * 4;
        s16x4 q = *(const s16x4*)&lds_w[wv][t0][addr];
        f32x4 o;
        o[0] = bf2f((unsigned short)q[0]) * rdt;
        o[1] = bf2f((unsigned short)q[1]) * rdt;
        o[2] = bf2f((unsigned short)q[2]) * rdt;
        o[3] = bf2f((unsigned short)q[3]) * rdt;
        *(f32x4*)&wout[(size_t)t0 * NCELLS + lane * 4] = o;
    }

    // ---- Phase 5: blended = (e' @ proto) * rden, 32 chunks of 16 dim-rows ----
    bf16x8 aw[8];
    #pragma unroll
    for (int ks = 0; ks < 8; ++ks)
        aw[ks] = *(const bf16x8*)&lds_w[wv][r][((ks * 4 + g) ^ (r & 7)) << 3];

    float* bout = out_blend + (size_t)tb * DIM;
    #pragma unroll 1
    for (int d2 = 0; d2 < 32; ++d2) {
        WAIT_BAR(4);   // allow ~4 newest stores in flight; forces the (older) stage done
        if (d2 < 31) stage8k(protoTL + (d2 + 1) * 4096, sbuf[(d2 + 1) & 1], tid);
        const unsigned short* bb = sbuf[d2 & 1];
        f32x4 acc = {0.f, 0.f, 0.f, 0.f};
        #pragma unroll
        for (int ks = 0; ks < 8; ++ks) {
            bf16x8 b = *(const bf16x8*)(bb + r * 256 + (((ks * 4 + g) ^ (r & 7)) << 3));
            acc = __builtin_amdgcn_mfma_f32_16x16x32_bf16(aw[ks], b, acc, 0, 0, 0);
        }
        #pragma unroll
        for (int j = 0; j < 4; ++j)
            bout[(size_t)(g * 4 + j) * DIM + d2 * 16 + r] = acc[j] * rden[j];
    }
}

// ---------------- launch ----------------
extern "C" void kernel_launch(void* const* d_in, const int* in_sizes, int n_in,
                              void* d_out, int out_size, void* d_ws, size_t ws_size,
                              hipStream_t stream) {
    const float* x           = (const float*)d_in[0];
    const float* proto       = (const float*)d_in[1];
    const float* grid        = (const float*)d_in[2];
    const float* temp_raw    = (const float*)d_in[3];
    const float* gate_logits = (const float*)d_in[4];

    float* out       = (float*)d_out;
    float* out_blend = out;                          // [N][512]
    float* out_w     = out + (size_t)NTOK * DIM;     // [N][256]

    char* ws = (char*)d_ws;
    unsigned short* pcombL  = (unsigned short*)(ws);            // 524288 B
    unsigned short* protoTL = (unsigned short*)(ws + 524288);   // 262144 B
    float* pp   = (float*)(ws + 786432);
    float* gg   = (float*)(ws + 787456);
    float* gate = (float*)(ws + 788480);
    float* invT = (float*)(ws + 789504);

    prep_kernel<<<dim3(NCELLS), dim3(256), 0, stream>>>(
        proto, grid, temp_raw, gate_logits, pcombL, protoTL, pp, gg, gate, invT);
    som_main<<<dim3(NTOK / 128), dim3(512), 0, stream>>>(
        x, pcombL, protoTL, pp, gg, gate, invT, out_blend, out_w);
}